// Round 1
// baseline (1485.721 us; speedup 1.0000x reference)
//
#include <hip/hip_runtime.h>
#include <hip/hip_bf16.h>

// LightGCN K=3 propagation on MI355X.
// Pipeline per launch (all on `stream`, graph-capture safe):
//   1. memset deg counters
//   2. histogram rows (atomicAdd int)
//   3. per-node norm factors a[r]=inv_sqrt*inv_deg, b[c]=inv_sqrt
//   4. single-block prefix scan -> CSR row_start + fill cursors
//   5. counting-sort scatter edges -> csr_col, csr_w (w = a[r]*b[c]*drop)
//   6. 3x SpMM gather passes: one wave per row, 64 lanes = 64 feature dims,
//      accumulate into d_out, final pass scales by 1/(K+1)=0.25.

#define DD 64   // feature dim

__global__ void count_kernel(const int* __restrict__ rows, int* __restrict__ cnt, int E) {
    int i = blockIdx.x * blockDim.x + threadIdx.x;
    int stride = gridDim.x * blockDim.x;
    for (; i < E; i += stride) atomicAdd(&cnt[rows[i]], 1);
}

__global__ void factor_kernel(const int* __restrict__ cnt,
                              float* __restrict__ a_fac,
                              float* __restrict__ b_fac, int n) {
    int i = blockIdx.x * blockDim.x + threadIdx.x;
    if (i >= n) return;
    float degf = (float)(cnt[i] + 1);            // +1 self loop
    float inv_deg = 1.0f / (degf + 1e-8f);
    float deg2 = degf * inv_deg;                 // == segment_sum of inv_deg copies
    float inv_sqrt = 1.0f / sqrtf(deg2 + 1e-8f);
    a_fac[i] = inv_sqrt * inv_deg;               // matches (inv_sqrt[row] * w) grouping
    b_fac[i] = inv_sqrt;
}

// single-block scan over N+ node degrees -> row_start[0..n], fill_pos[i]=row_start[i]
__global__ void scan_kernel(const int* __restrict__ cnt,
                            int* __restrict__ row_start,
                            int* __restrict__ fill_pos, int n) {
    __shared__ int sh[1024];
    int tid = threadIdx.x;
    int chunk = (n + 1023) >> 10;
    int beg = tid * chunk;
    int end = beg + chunk; if (end > n) end = n;
    int s = 0;
    for (int i = beg; i < end; ++i) s += cnt[i] + 1;
    sh[tid] = s;
    __syncthreads();
    // Hillis-Steele inclusive scan
    for (int off = 1; off < 1024; off <<= 1) {
        int v = sh[tid];
        int add = (tid >= off) ? sh[tid - off] : 0;
        __syncthreads();
        sh[tid] = v + add;
        __syncthreads();
    }
    int excl = (tid == 0) ? 0 : sh[tid - 1];
    for (int i = beg; i < end; ++i) {
        row_start[i] = excl;
        fill_pos[i] = excl;
        excl += cnt[i] + 1;
    }
    if (tid == 1023) row_start[n] = sh[1023];
}

__global__ void scatter_kernel(const int* __restrict__ ei,      // [2*E] rows then cols
                               const float* __restrict__ drop,  // [E+n]
                               const float* __restrict__ a_fac,
                               const float* __restrict__ b_fac,
                               int* __restrict__ fill_pos,
                               int* __restrict__ csr_col,
                               float* __restrict__ csr_w,
                               int E, int n) {
    int i = blockIdx.x * blockDim.x + threadIdx.x;
    int stride = gridDim.x * blockDim.x;
    int total = E + n;
    for (; i < total; i += stride) {
        int r, c;
        if (i < E) { r = ei[i]; c = ei[E + i]; }
        else       { r = i - E; c = r; }            // self loop
        float w = (a_fac[r] * b_fac[c]) * drop[i];
        int pos = atomicAdd(&fill_pos[r], 1);
        csr_col[pos] = c;
        csr_w[pos]   = w;
    }
}

// one wave (64 lanes) per destination row; lane = feature dim
__global__ void spmm_kernel(const int* __restrict__ row_start,
                            const int* __restrict__ csr_col,
                            const float* __restrict__ csr_w,
                            const float* __restrict__ h_in,
                            float* __restrict__ h_out,
                            const float* __restrict__ acc_in,
                            float* __restrict__ acc_out,
                            float scale, int n) {
    int wave_global = (blockIdx.x * blockDim.x + threadIdx.x) >> 6;
    int lane = threadIdx.x & 63;
    if (wave_global >= n) return;
    int beg = row_start[wave_global];
    int end = row_start[wave_global + 1];
    float sum = 0.0f;
    for (int j = beg; j < end; ++j) {
        int c   = csr_col[j];
        float w = csr_w[j];
        sum += w * h_in[c * DD + lane];
    }
    int idx = wave_global * DD + lane;
    h_out[idx] = sum;
    acc_out[idx] = (acc_in[idx] + sum) * scale;
}

extern "C" void kernel_launch(void* const* d_in, const int* in_sizes, int n_in,
                              void* d_out, int out_size, void* d_ws, size_t ws_size,
                              hipStream_t stream) {
    const float* x    = (const float*)d_in[0];
    const int*   ei   = (const int*)d_in[1];
    const float* drop = (const float*)d_in[2];
    float* out = (float*)d_out;

    const int N = in_sizes[0] / DD;      // 100000
    const int E = in_sizes[1] / 2;       // 3200000
    const int TOT = E + N;

    // workspace carve (256B aligned)
    char* p = (char*)d_ws;
    auto alloc = [&](size_t bytes) -> void* {
        void* r = (void*)p;
        p += (bytes + 255) & ~(size_t)255;
        return r;
    };
    int*   deg_cnt   = (int*)  alloc((size_t)N * 4);
    int*   row_start = (int*)  alloc((size_t)(N + 1) * 4);
    int*   fill_pos  = (int*)  alloc((size_t)N * 4);
    float* a_fac     = (float*)alloc((size_t)N * 4);
    float* b_fac     = (float*)alloc((size_t)N * 4);
    int*   csr_col   = (int*)  alloc((size_t)TOT * 4);
    float* csr_w     = (float*)alloc((size_t)TOT * 4);
    float* h_a       = (float*)alloc((size_t)N * DD * 4);
    float* h_b       = (float*)alloc((size_t)N * DD * 4);

    hipMemsetAsync(deg_cnt, 0, (size_t)N * 4, stream);

    count_kernel<<<2048, 256, 0, stream>>>(ei, deg_cnt, E);
    factor_kernel<<<(N + 255) / 256, 256, 0, stream>>>(deg_cnt, a_fac, b_fac, N);
    scan_kernel<<<1, 1024, 0, stream>>>(deg_cnt, row_start, fill_pos, N);
    scatter_kernel<<<2048, 256, 0, stream>>>(ei, drop, a_fac, b_fac,
                                             fill_pos, csr_col, csr_w, E, N);

    const int rows_per_block = 256 / 64;
    const int spmm_grid = (N + rows_per_block - 1) / rows_per_block;

    // hop 1: h_a = A x ; out = x + h_a
    spmm_kernel<<<spmm_grid, 256, 0, stream>>>(row_start, csr_col, csr_w,
                                               x, h_a, x, out, 1.0f, N);
    // hop 2: h_b = A h_a ; out += h_b
    spmm_kernel<<<spmm_grid, 256, 0, stream>>>(row_start, csr_col, csr_w,
                                               h_a, h_b, out, out, 1.0f, N);
    // hop 3: h_a = A h_b ; out = (out + h_a) * 0.25
    spmm_kernel<<<spmm_grid, 256, 0, stream>>>(row_start, csr_col, csr_w,
                                               h_b, h_a, out, out, 0.25f, N);
}

// Round 2
// 956.179 us; speedup vs baseline: 1.5538x; 1.5538x over previous
//
#include <hip/hip_runtime.h>
#include <hip/hip_bf16.h>

// LightGCN K=3 propagation on MI355X.
// R2: (a) SpMM gather loop unrolled x8 with independent accumulators for MLP
//     (b) (col,weight) packed into one 8B word -> 1 scattered store per edge,
//         1 uniform 8B load per edge per SpMM pass.

#define DD 64   // feature dim

__global__ void count_kernel(const int* __restrict__ rows, int* __restrict__ cnt, int E) {
    int i = blockIdx.x * blockDim.x + threadIdx.x;
    int stride = gridDim.x * blockDim.x;
    for (; i < E; i += stride) atomicAdd(&cnt[rows[i]], 1);
}

__global__ void factor_kernel(const int* __restrict__ cnt,
                              float* __restrict__ a_fac,
                              float* __restrict__ b_fac, int n) {
    int i = blockIdx.x * blockDim.x + threadIdx.x;
    if (i >= n) return;
    float degf = (float)(cnt[i] + 1);            // +1 self loop
    float inv_deg = 1.0f / (degf + 1e-8f);
    float deg2 = degf * inv_deg;                 // == segment_sum of inv_deg copies
    float inv_sqrt = 1.0f / sqrtf(deg2 + 1e-8f);
    a_fac[i] = inv_sqrt * inv_deg;               // matches (inv_sqrt[row] * w) grouping
    b_fac[i] = inv_sqrt;
}

// single-block scan over node degrees -> row_start[0..n], fill_pos[i]=row_start[i]
__global__ void scan_kernel(const int* __restrict__ cnt,
                            int* __restrict__ row_start,
                            int* __restrict__ fill_pos, int n) {
    __shared__ int sh[1024];
    int tid = threadIdx.x;
    int chunk = (n + 1023) >> 10;
    int beg = tid * chunk;
    int end = beg + chunk; if (end > n) end = n;
    int s = 0;
    for (int i = beg; i < end; ++i) s += cnt[i] + 1;
    sh[tid] = s;
    __syncthreads();
    for (int off = 1; off < 1024; off <<= 1) {
        int v = sh[tid];
        int add = (tid >= off) ? sh[tid - off] : 0;
        __syncthreads();
        sh[tid] = v + add;
        __syncthreads();
    }
    int excl = (tid == 0) ? 0 : sh[tid - 1];
    for (int i = beg; i < end; ++i) {
        row_start[i] = excl;
        fill_pos[i] = excl;
        excl += cnt[i] + 1;
    }
    if (tid == 1023) row_start[n] = sh[1023];
}

__global__ void scatter_kernel(const int* __restrict__ ei,      // [2*E] rows then cols
                               const float* __restrict__ drop,  // [E+n]
                               const float* __restrict__ a_fac,
                               const float* __restrict__ b_fac,
                               int* __restrict__ fill_pos,
                               unsigned long long* __restrict__ csr_ew,
                               int E, int n) {
    int i = blockIdx.x * blockDim.x + threadIdx.x;
    int stride = gridDim.x * blockDim.x;
    int total = E + n;
    for (; i < total; i += stride) {
        int r, c;
        if (i < E) { r = ei[i]; c = ei[E + i]; }
        else       { r = i - E; c = r; }            // self loop
        float w = (a_fac[r] * b_fac[c]) * drop[i];
        int pos = atomicAdd(&fill_pos[r], 1);
        unsigned long long packed =
            ((unsigned long long)__float_as_uint(w) << 32) | (unsigned int)c;
        csr_ew[pos] = packed;
    }
}

// one wave (64 lanes) per destination row; lane = feature dim.
// Edge loop unrolled x8: 8 independent gathers in flight per wave.
__global__ void __launch_bounds__(256)
spmm_kernel(const int* __restrict__ row_start,
            const unsigned long long* __restrict__ csr_ew,
            const float* __restrict__ h_in,
            float* __restrict__ h_out,
            const float* __restrict__ acc_in,
            float* __restrict__ acc_out,
            float scale, int n) {
    int wave_global = (blockIdx.x * blockDim.x + threadIdx.x) >> 6;
    int lane = threadIdx.x & 63;
    if (wave_global >= n) return;
    int beg = row_start[wave_global];
    int end = row_start[wave_global + 1];

    float s0 = 0.f, s1 = 0.f, s2 = 0.f, s3 = 0.f;
    float s4 = 0.f, s5 = 0.f, s6 = 0.f, s7 = 0.f;

    int j = beg;
    int main_end = beg + ((end - beg) & ~7);
    for (; j < main_end; j += 8) {
        unsigned long long e0 = csr_ew[j + 0];
        unsigned long long e1 = csr_ew[j + 1];
        unsigned long long e2 = csr_ew[j + 2];
        unsigned long long e3 = csr_ew[j + 3];
        unsigned long long e4 = csr_ew[j + 4];
        unsigned long long e5 = csr_ew[j + 5];
        unsigned long long e6 = csr_ew[j + 6];
        unsigned long long e7 = csr_ew[j + 7];
        int c0 = (int)(unsigned int)e0; float w0 = __uint_as_float((unsigned int)(e0 >> 32));
        int c1 = (int)(unsigned int)e1; float w1 = __uint_as_float((unsigned int)(e1 >> 32));
        int c2 = (int)(unsigned int)e2; float w2 = __uint_as_float((unsigned int)(e2 >> 32));
        int c3 = (int)(unsigned int)e3; float w3 = __uint_as_float((unsigned int)(e3 >> 32));
        int c4 = (int)(unsigned int)e4; float w4 = __uint_as_float((unsigned int)(e4 >> 32));
        int c5 = (int)(unsigned int)e5; float w5 = __uint_as_float((unsigned int)(e5 >> 32));
        int c6 = (int)(unsigned int)e6; float w6 = __uint_as_float((unsigned int)(e6 >> 32));
        int c7 = (int)(unsigned int)e7; float w7 = __uint_as_float((unsigned int)(e7 >> 32));
        float v0 = h_in[c0 * DD + lane];
        float v1 = h_in[c1 * DD + lane];
        float v2 = h_in[c2 * DD + lane];
        float v3 = h_in[c3 * DD + lane];
        float v4 = h_in[c4 * DD + lane];
        float v5 = h_in[c5 * DD + lane];
        float v6 = h_in[c6 * DD + lane];
        float v7 = h_in[c7 * DD + lane];
        s0 += w0 * v0; s1 += w1 * v1; s2 += w2 * v2; s3 += w3 * v3;
        s4 += w4 * v4; s5 += w5 * v5; s6 += w6 * v6; s7 += w7 * v7;
    }
    for (; j < end; ++j) {
        unsigned long long e = csr_ew[j];
        int c = (int)(unsigned int)e;
        float w = __uint_as_float((unsigned int)(e >> 32));
        s0 += w * h_in[c * DD + lane];
    }
    float sum = ((s0 + s1) + (s2 + s3)) + ((s4 + s5) + (s6 + s7));

    int idx = wave_global * DD + lane;
    h_out[idx] = sum;
    acc_out[idx] = (acc_in[idx] + sum) * scale;
}

extern "C" void kernel_launch(void* const* d_in, const int* in_sizes, int n_in,
                              void* d_out, int out_size, void* d_ws, size_t ws_size,
                              hipStream_t stream) {
    const float* x    = (const float*)d_in[0];
    const int*   ei   = (const int*)d_in[1];
    const float* drop = (const float*)d_in[2];
    float* out = (float*)d_out;

    const int N = in_sizes[0] / DD;      // 100000
    const int E = in_sizes[1] / 2;       // 3200000
    const int TOT = E + N;

    // workspace carve (256B aligned)
    char* p = (char*)d_ws;
    auto alloc = [&](size_t bytes) -> void* {
        void* r = (void*)p;
        p += (bytes + 255) & ~(size_t)255;
        return r;
    };
    int*   deg_cnt   = (int*)  alloc((size_t)N * 4);
    int*   row_start = (int*)  alloc((size_t)(N + 1) * 4);
    int*   fill_pos  = (int*)  alloc((size_t)N * 4);
    float* a_fac     = (float*)alloc((size_t)N * 4);
    float* b_fac     = (float*)alloc((size_t)N * 4);
    unsigned long long* csr_ew = (unsigned long long*)alloc((size_t)TOT * 8);
    float* h_a       = (float*)alloc((size_t)N * DD * 4);
    float* h_b       = (float*)alloc((size_t)N * DD * 4);

    hipMemsetAsync(deg_cnt, 0, (size_t)N * 4, stream);

    count_kernel<<<2048, 256, 0, stream>>>(ei, deg_cnt, E);
    factor_kernel<<<(N + 255) / 256, 256, 0, stream>>>(deg_cnt, a_fac, b_fac, N);
    scan_kernel<<<1, 1024, 0, stream>>>(deg_cnt, row_start, fill_pos, N);
    scatter_kernel<<<2048, 256, 0, stream>>>(ei, drop, a_fac, b_fac,
                                             fill_pos, csr_ew, E, N);

    const int rows_per_block = 256 / 64;
    const int spmm_grid = (N + rows_per_block - 1) / rows_per_block;

    // hop 1: h_a = A x ; out = x + h_a
    spmm_kernel<<<spmm_grid, 256, 0, stream>>>(row_start, csr_ew,
                                               x, h_a, x, out, 1.0f, N);
    // hop 2: h_b = A h_a ; out += h_b
    spmm_kernel<<<spmm_grid, 256, 0, stream>>>(row_start, csr_ew,
                                               h_a, h_b, out, out, 1.0f, N);
    // hop 3: h_a = A h_b ; out = (out + h_a) * 0.25
    spmm_kernel<<<spmm_grid, 256, 0, stream>>>(row_start, csr_ew,
                                               h_b, h_a, out, out, 0.25f, N);
}

// Round 4
// 730.748 us; speedup vs baseline: 2.0332x; 1.3085x over previous
//
#include <hip/hip_runtime.h>
#include <hip/hip_bf16.h>

// LightGCN K=3 propagation on MI355X.
// R3 (resubmit; previous round hit GPU-acquisition timeout): replace the
// 1-block (229us!) prefix scan with a 3-phase device-wide scan (~196 blocks).
// Everything else unchanged from R2.

#define DD 64            // feature dim
#define SCAN_BLOCK 256
#define SCAN_ITEMS 2
#define SCAN_CHUNK (SCAN_BLOCK * SCAN_ITEMS)   // 512 elems per block

__global__ void count_kernel(const int* __restrict__ rows, int* __restrict__ cnt, int E) {
    int i = blockIdx.x * blockDim.x + threadIdx.x;
    int stride = gridDim.x * blockDim.x;
    for (; i < E; i += stride) atomicAdd(&cnt[rows[i]], 1);
}

__global__ void factor_kernel(const int* __restrict__ cnt,
                              float* __restrict__ a_fac,
                              float* __restrict__ b_fac, int n) {
    int i = blockIdx.x * blockDim.x + threadIdx.x;
    if (i >= n) return;
    float degf = (float)(cnt[i] + 1);            // +1 self loop
    float inv_deg = 1.0f / (degf + 1e-8f);
    float deg2 = degf * inv_deg;                 // == segment_sum of inv_deg copies
    float inv_sqrt = 1.0f / sqrtf(deg2 + 1e-8f);
    a_fac[i] = inv_sqrt * inv_deg;               // matches (inv_sqrt[row] * w) grouping
    b_fac[i] = inv_sqrt;
}

// ---- 3-phase device-wide exclusive scan of (cnt[i]+1) ----
__global__ void scan_phase1(const int* __restrict__ cnt,
                            int* __restrict__ blk_sum, int n) {
    __shared__ int sh[SCAN_BLOCK];
    int b = blockIdx.x, tid = threadIdx.x;
    int base = b * SCAN_CHUNK + tid * SCAN_ITEMS;
    int s = 0;
#pragma unroll
    for (int k = 0; k < SCAN_ITEMS; ++k) {
        int i = base + k;
        if (i < n) s += cnt[i] + 1;
    }
    sh[tid] = s;
    __syncthreads();
    for (int off = SCAN_BLOCK / 2; off > 0; off >>= 1) {
        if (tid < off) sh[tid] += sh[tid + off];
        __syncthreads();
    }
    if (tid == 0) blk_sum[b] = sh[0];
}

// single block; robust for nb up to 256*64
__global__ void scan_phase2(const int* __restrict__ blk_sum,
                            int* __restrict__ blk_off, int nb) {
    __shared__ int sh[256];
    int tid = threadIdx.x;
    int m = (nb + 255) >> 8;                 // partials per thread
    int base = tid * m;
    int s = 0;
    for (int k = 0; k < m; ++k) {
        int i = base + k;
        if (i < nb) s += blk_sum[i];
    }
    sh[tid] = s;
    __syncthreads();
    for (int off = 1; off < 256; off <<= 1) {
        int v = sh[tid];
        int add = (tid >= off) ? sh[tid - off] : 0;
        __syncthreads();
        sh[tid] = v + add;
        __syncthreads();
    }
    int excl = (tid == 0) ? 0 : sh[tid - 1];
    for (int k = 0; k < m; ++k) {
        int i = base + k;
        if (i < nb) {
            blk_off[i] = excl;
            excl += blk_sum[i];
        }
    }
}

__global__ void scan_phase3(const int* __restrict__ cnt,
                            const int* __restrict__ blk_off,
                            int* __restrict__ row_start,
                            int* __restrict__ fill_pos, int n) {
    __shared__ int sh[SCAN_BLOCK];
    int b = blockIdx.x, tid = threadIdx.x;
    int base = b * SCAN_CHUNK + tid * SCAN_ITEMS;
    int loc[SCAN_ITEMS];
    int s = 0;
#pragma unroll
    for (int k = 0; k < SCAN_ITEMS; ++k) {
        int i = base + k;
        int v = (i < n) ? cnt[i] + 1 : 0;
        loc[k] = s;
        s += v;
    }
    sh[tid] = s;
    __syncthreads();
    for (int off = 1; off < SCAN_BLOCK; off <<= 1) {
        int v = sh[tid];
        int add = (tid >= off) ? sh[tid - off] : 0;
        __syncthreads();
        sh[tid] = v + add;
        __syncthreads();
    }
    int thr_off = blk_off[b] + ((tid == 0) ? 0 : sh[tid - 1]);
#pragma unroll
    for (int k = 0; k < SCAN_ITEMS; ++k) {
        int i = base + k;
        if (i < n) {
            int v = thr_off + loc[k];
            row_start[i] = v;
            fill_pos[i] = v;
            if (i == n - 1) row_start[n] = v + cnt[i] + 1;
        }
    }
}

__global__ void scatter_kernel(const int* __restrict__ ei,      // [2*E] rows then cols
                               const float* __restrict__ drop,  // [E+n]
                               const float* __restrict__ a_fac,
                               const float* __restrict__ b_fac,
                               int* __restrict__ fill_pos,
                               unsigned long long* __restrict__ csr_ew,
                               int E, int n) {
    int i = blockIdx.x * blockDim.x + threadIdx.x;
    int stride = gridDim.x * blockDim.x;
    int total = E + n;
    for (; i < total; i += stride) {
        int r, c;
        if (i < E) { r = ei[i]; c = ei[E + i]; }
        else       { r = i - E; c = r; }            // self loop
        float w = (a_fac[r] * b_fac[c]) * drop[i];
        int pos = atomicAdd(&fill_pos[r], 1);
        unsigned long long packed =
            ((unsigned long long)__float_as_uint(w) << 32) | (unsigned int)c;
        csr_ew[pos] = packed;
    }
}

// one wave (64 lanes) per destination row; lane = feature dim.
// Edge loop unrolled x8: 8 independent gathers in flight per wave.
__global__ void __launch_bounds__(256)
spmm_kernel(const int* __restrict__ row_start,
            const unsigned long long* __restrict__ csr_ew,
            const float* __restrict__ h_in,
            float* __restrict__ h_out,
            const float* __restrict__ acc_in,
            float* __restrict__ acc_out,
            float scale, int n) {
    int wave_global = (blockIdx.x * blockDim.x + threadIdx.x) >> 6;
    int lane = threadIdx.x & 63;
    if (wave_global >= n) return;
    int beg = row_start[wave_global];
    int end = row_start[wave_global + 1];

    float s0 = 0.f, s1 = 0.f, s2 = 0.f, s3 = 0.f;
    float s4 = 0.f, s5 = 0.f, s6 = 0.f, s7 = 0.f;

    int j = beg;
    int main_end = beg + ((end - beg) & ~7);
    for (; j < main_end; j += 8) {
        unsigned long long e0 = csr_ew[j + 0];
        unsigned long long e1 = csr_ew[j + 1];
        unsigned long long e2 = csr_ew[j + 2];
        unsigned long long e3 = csr_ew[j + 3];
        unsigned long long e4 = csr_ew[j + 4];
        unsigned long long e5 = csr_ew[j + 5];
        unsigned long long e6 = csr_ew[j + 6];
        unsigned long long e7 = csr_ew[j + 7];
        int c0 = (int)(unsigned int)e0; float w0 = __uint_as_float((unsigned int)(e0 >> 32));
        int c1 = (int)(unsigned int)e1; float w1 = __uint_as_float((unsigned int)(e1 >> 32));
        int c2 = (int)(unsigned int)e2; float w2 = __uint_as_float((unsigned int)(e2 >> 32));
        int c3 = (int)(unsigned int)e3; float w3 = __uint_as_float((unsigned int)(e3 >> 32));
        int c4 = (int)(unsigned int)e4; float w4 = __uint_as_float((unsigned int)(e4 >> 32));
        int c5 = (int)(unsigned int)e5; float w5 = __uint_as_float((unsigned int)(e5 >> 32));
        int c6 = (int)(unsigned int)e6; float w6 = __uint_as_float((unsigned int)(e6 >> 32));
        int c7 = (int)(unsigned int)e7; float w7 = __uint_as_float((unsigned int)(e7 >> 32));
        float v0 = h_in[c0 * DD + lane];
        float v1 = h_in[c1 * DD + lane];
        float v2 = h_in[c2 * DD + lane];
        float v3 = h_in[c3 * DD + lane];
        float v4 = h_in[c4 * DD + lane];
        float v5 = h_in[c5 * DD + lane];
        float v6 = h_in[c6 * DD + lane];
        float v7 = h_in[c7 * DD + lane];
        s0 += w0 * v0; s1 += w1 * v1; s2 += w2 * v2; s3 += w3 * v3;
        s4 += w4 * v4; s5 += w5 * v5; s6 += w6 * v6; s7 += w7 * v7;
    }
    for (; j < end; ++j) {
        unsigned long long e = csr_ew[j];
        int c = (int)(unsigned int)e;
        float w = __uint_as_float((unsigned int)(e >> 32));
        s0 += w * h_in[c * DD + lane];
    }
    float sum = ((s0 + s1) + (s2 + s3)) + ((s4 + s5) + (s6 + s7));

    int idx = wave_global * DD + lane;
    h_out[idx] = sum;
    acc_out[idx] = (acc_in[idx] + sum) * scale;
}

extern "C" void kernel_launch(void* const* d_in, const int* in_sizes, int n_in,
                              void* d_out, int out_size, void* d_ws, size_t ws_size,
                              hipStream_t stream) {
    const float* x    = (const float*)d_in[0];
    const int*   ei   = (const int*)d_in[1];
    const float* drop = (const float*)d_in[2];
    float* out = (float*)d_out;

    const int N = in_sizes[0] / DD;      // 100000
    const int E = in_sizes[1] / 2;       // 3200000
    const int TOT = E + N;
    const int NB = (N + SCAN_CHUNK - 1) / SCAN_CHUNK;   // scan blocks (~196)

    // workspace carve (256B aligned)
    char* p = (char*)d_ws;
    auto alloc = [&](size_t bytes) -> void* {
        void* r = (void*)p;
        p += (bytes + 255) & ~(size_t)255;
        return r;
    };
    int*   deg_cnt   = (int*)  alloc((size_t)N * 4);
    int*   row_start = (int*)  alloc((size_t)(N + 1) * 4);
    int*   fill_pos  = (int*)  alloc((size_t)N * 4);
    float* a_fac     = (float*)alloc((size_t)N * 4);
    float* b_fac     = (float*)alloc((size_t)N * 4);
    int*   blk_sum   = (int*)  alloc((size_t)NB * 4);
    int*   blk_off   = (int*)  alloc((size_t)NB * 4);
    unsigned long long* csr_ew = (unsigned long long*)alloc((size_t)TOT * 8);
    float* h_a       = (float*)alloc((size_t)N * DD * 4);
    float* h_b       = (float*)alloc((size_t)N * DD * 4);

    hipMemsetAsync(deg_cnt, 0, (size_t)N * 4, stream);

    count_kernel<<<2048, 256, 0, stream>>>(ei, deg_cnt, E);
    factor_kernel<<<(N + 255) / 256, 256, 0, stream>>>(deg_cnt, a_fac, b_fac, N);
    scan_phase1<<<NB, SCAN_BLOCK, 0, stream>>>(deg_cnt, blk_sum, N);
    scan_phase2<<<1, 256, 0, stream>>>(blk_sum, blk_off, NB);
    scan_phase3<<<NB, SCAN_BLOCK, 0, stream>>>(deg_cnt, blk_off, row_start, fill_pos, N);
    scatter_kernel<<<2048, 256, 0, stream>>>(ei, drop, a_fac, b_fac,
                                             fill_pos, csr_ew, E, N);

    const int rows_per_block = 256 / 64;
    const int spmm_grid = (N + rows_per_block - 1) / rows_per_block;

    // hop 1: h_a = A x ; out = x + h_a
    spmm_kernel<<<spmm_grid, 256, 0, stream>>>(row_start, csr_ew,
                                               x, h_a, x, out, 1.0f, N);
    // hop 2: h_b = A h_a ; out += h_b
    spmm_kernel<<<spmm_grid, 256, 0, stream>>>(row_start, csr_ew,
                                               h_a, h_b, out, out, 1.0f, N);
    // hop 3: h_a = A h_b ; out = (out + h_a) * 0.25
    spmm_kernel<<<spmm_grid, 256, 0, stream>>>(row_start, csr_ew,
                                               h_b, h_a, out, out, 0.25f, N);
}